// Round 2
// baseline (322.950 us; speedup 1.0000x reference)
//
#include <hip/hip_runtime.h>
#include <hip/hip_bf16.h>

#define N_NODES 30000
#define N_EDGES 480000
#define IN_CH   1024
#define OUT_CH  128
#define MAX_DEG 48

typedef float   f32x4  __attribute__((ext_vector_type(4)));
typedef __bf16  bf16x8 __attribute__((ext_vector_type(8)));
typedef unsigned short ushort8 __attribute__((ext_vector_type(8)));

__device__ __forceinline__ unsigned short f2bf(float f) {
  unsigned int u = __builtin_bit_cast(unsigned int, f);
  u += 0x7fffu + ((u >> 16) & 1u);          // RTNE
  return (unsigned short)(u >> 16);
}

// ---------------------------------------------------------------------------
// Kernel 1: W [1024][128] fp32  ->  Wt [128][1024] bf16 (transposed)
// ---------------------------------------------------------------------------
__global__ __launch_bounds__(256) void convert_W(const float* __restrict__ W,
                                                 unsigned short* __restrict__ Wt) {
  int idx = blockIdx.x * 256 + threadIdx.x;      // over Wt, 131072 elems
  int n = idx >> 10;                              // 0..127
  int k = idx & 1023;                             // 0..1023
  Wt[idx] = f2bf(W[k * OUT_CH + n]);
}

// ---------------------------------------------------------------------------
// Kernel 2: adjacency build (edges + self-loops), atomic slot assignment
// ---------------------------------------------------------------------------
__global__ __launch_bounds__(256) void build_adj(const int* __restrict__ ei,
                                                 int* __restrict__ deg,
                                                 int* __restrict__ adj) {
  int i = blockIdx.x * blockDim.x + threadIdx.x;
  const int total = N_EDGES + N_NODES;
  if (i >= total) return;
  int src, dst;
  if (i < N_EDGES) { src = ei[i]; dst = ei[N_EDGES + i]; }
  else             { src = i - N_EDGES; dst = src; }     // self-loop
  int slot = atomicAdd(&deg[dst], 1);
  if (slot < MAX_DEG) adj[dst * MAX_DEG + slot] = src;
}

// ---------------------------------------------------------------------------
// Kernel 3: h = x @ W + b  via bf16 MFMA, K-split across 4 waves.
// Block = 256 thr (4 waves), tile 16 rows x 128 cols. Wave w does K-range
// [w*256, (w+1)*256), then padded-LDS cross-wave reduction; wave 0 writes.
// Grid 1875 blocks -> ~29 waves/CU available (was 7 -> latency-bound).
// ---------------------------------------------------------------------------
#define RED_STRIDE 36   // floats; 144B: 16B-aligned for b128, rotates banks

__global__ __launch_bounds__(256) void gemm_h(const float* __restrict__ x,
                                              const unsigned short* __restrict__ Wt,
                                              const float* __restrict__ b,
                                              float* __restrict__ h) {
  const int tid  = threadIdx.x;
  const int wave = tid >> 6;
  const int lane = tid & 63;
  const int l16  = lane & 15;
  const int g4   = lane >> 4;
  const int m0   = blockIdx.x * 16;               // 30000 % 16 == 0: no OOB rows
  const int arow = m0 + l16;
  const int kbase = wave * 256 + g4 * 8;
  const float* aptr = x + (size_t)arow * IN_CH + kbase;
  const unsigned short* bptr = Wt + l16 * IN_CH + kbase;

  f32x4 acc[8];
#pragma unroll
  for (int i = 0; i < 8; ++i) acc[i] = (f32x4){0.f, 0.f, 0.f, 0.f};

#pragma unroll
  for (int k0 = 0; k0 < 256; k0 += 32) {
    f32x4 a0 = *(const f32x4*)(aptr + k0);
    f32x4 a1 = *(const f32x4*)(aptr + k0 + 4);
    ushort8 af;
    af[0] = f2bf(a0[0]); af[1] = f2bf(a0[1]); af[2] = f2bf(a0[2]); af[3] = f2bf(a0[3]);
    af[4] = f2bf(a1[0]); af[5] = f2bf(a1[1]); af[6] = f2bf(a1[2]); af[7] = f2bf(a1[3]);
    bf16x8 av = __builtin_bit_cast(bf16x8, af);
#pragma unroll
    for (int nn = 0; nn < 8; ++nn) {
      ushort8 bu = *(const ushort8*)(bptr + nn * 16 * IN_CH + k0);
      bf16x8 bv = __builtin_bit_cast(bf16x8, bu);
      acc[nn] = __builtin_amdgcn_mfma_f32_16x16x32_bf16(av, bv, acc[nn], 0, 0, 0);
    }
  }

  // Cross-wave reduction: waves 1..3 dump acc to LDS, wave 0 sums + writes.
  __shared__ float red[3 * 64 * RED_STRIDE];      // 27648 B
  if (wave >= 1) {
    float* dst = &red[((wave - 1) * 64 + lane) * RED_STRIDE];
#pragma unroll
    for (int nn = 0; nn < 8; ++nn)
      *(f32x4*)(dst + nn * 4) = acc[nn];
  }
  __syncthreads();
  if (wave == 0) {
#pragma unroll
    for (int s = 0; s < 3; ++s) {
      const float* src = &red[(s * 64 + lane) * RED_STRIDE];
#pragma unroll
      for (int nn = 0; nn < 8; ++nn) {
        f32x4 v = *(const f32x4*)(src + nn * 4);
        acc[nn] += v;
      }
    }
    // C/D layout (verified m89/m91): col = lane&15, row = (lane>>4)*4 + i
    const int crow = m0 + g4 * 4;
#pragma unroll
    for (int nn = 0; nn < 8; ++nn) {
      const int col = nn * 16 + l16;
      const float bias = b[col];                  // median(h+b) == median(h)+b
#pragma unroll
      for (int i = 0; i < 4; ++i) {
        int r = crow + i;
        h[(size_t)r * OUT_CH + col] = acc[nn][i] + bias;
      }
    }
  }
}

// ---------------------------------------------------------------------------
// Kernel 4: per-node, per-channel lower median via register sorting network
// ---------------------------------------------------------------------------
template <int NS>
__device__ __forceinline__ void batcher_sort(float (&a)[NS]) {
#pragma unroll
  for (int p = 1; p < NS; p <<= 1) {
#pragma unroll
    for (int k = p; k >= 1; k >>= 1) {
#pragma unroll
      for (int j = k % p; j + k < NS; j += 2 * k) {
#pragma unroll
        for (int i = 0; i < k; ++i) {
          if (i + j + k < NS) {
            if ((i + j) / (2 * p) == (i + j + k) / (2 * p)) {
              float lo = fminf(a[i + j], a[i + j + k]);
              float hi = fmaxf(a[i + j], a[i + j + k]);
              a[i + j] = lo;
              a[i + j + k] = hi;
            }
          }
        }
      }
    }
  }
}

template <int NS>
__device__ __forceinline__ float med_n(const float* __restrict__ h,
                                       const int* nbrs, int d, int m, int ch) {
  float a[NS];
#pragma unroll
  for (int j = 0; j < NS; ++j) {
    if (j < d) a[j] = h[(size_t)nbrs[j] * OUT_CH + ch];
    else       a[j] = 1e30f;
  }
  batcher_sort<NS>(a);
  float med = a[0];
#pragma unroll
  for (int j = 1; j < NS; ++j) med = (j == m) ? a[j] : med;
  return med;
}

__global__ __launch_bounds__(128) void median_kernel(const float* __restrict__ h,
                                                     const int* __restrict__ adj,
                                                     const int* __restrict__ deg,
                                                     float* __restrict__ out) {
  __shared__ int nbrs[64];
  const int node = blockIdx.x;
  const int ch   = threadIdx.x;
  int d = deg[node];
  if (d > MAX_DEG) d = MAX_DEG;
  if (ch < 64) nbrs[ch] = (ch < d && ch < MAX_DEG) ? adj[node * MAX_DEG + ch] : 0;
  __syncthreads();
  const int m = (d - 1) >> 1;   // lower median index; d >= 1 (self-loop)

  float med;
  if (d <= 8)       med = med_n<8>(h, nbrs, d, m, ch);
  else if (d <= 16) med = med_n<16>(h, nbrs, d, m, ch);
  else if (d <= 32) med = med_n<32>(h, nbrs, d, m, ch);
  else              med = med_n<64>(h, nbrs, d, m, ch);

  out[(size_t)node * OUT_CH + ch] = med;
}

// ---------------------------------------------------------------------------
extern "C" void kernel_launch(void* const* d_in, const int* in_sizes, int n_in,
                              void* d_out, int out_size, void* d_ws, size_t ws_size,
                              hipStream_t stream) {
  const float* x  = (const float*)d_in[0];
  const int*   ei = (const int*)d_in[1];
  const float* W  = (const float*)d_in[2];
  const float* b  = (const float*)d_in[3];
  float* out = (float*)d_out;

  char* ws = (char*)d_ws;
  float*          h   = (float*)ws;                                  // 15,360,000 B
  unsigned short* Wt  = (unsigned short*)(ws + 15360000);             //    262,144 B
  int*            deg = (int*)(ws + 15360000 + 262144);               //    120,000 B
  int*            adj = (int*)(ws + 15360000 + 262144 + 120000);      //  5,760,000 B

  hipMemsetAsync(deg, 0, N_NODES * sizeof(int), stream);
  convert_W<<<dim3(131072 / 256), dim3(256), 0, stream>>>(W, Wt);
  build_adj<<<dim3((N_EDGES + N_NODES + 255) / 256), dim3(256), 0, stream>>>(ei, deg, adj);
  gemm_h<<<dim3(N_NODES / 16), dim3(256), 0, stream>>>(x, Wt, b, h);
  median_kernel<<<dim3(N_NODES), dim3(128), 0, stream>>>(h, adj, deg, out);
}

// Round 3
// 294.806 us; speedup vs baseline: 1.0955x; 1.0955x over previous
//
#include <hip/hip_runtime.h>
#include <hip/hip_bf16.h>

#define N_NODES 30000
#define N_EDGES 480000
#define IN_CH   1024
#define OUT_CH  128
#define MAX_DEG 48

#define BM 128
#define BK 64
#define NSTEP (IN_CH / BK)   // 16

typedef float   f32x4  __attribute__((ext_vector_type(4)));
typedef __bf16  bf16x8 __attribute__((ext_vector_type(8)));
typedef unsigned short ushort8 __attribute__((ext_vector_type(8)));

__device__ __forceinline__ unsigned short f2bf(float f) {
  unsigned int u = __builtin_bit_cast(unsigned int, f);
  u += 0x7fffu + ((u >> 16) & 1u);          // RTNE
  return (unsigned short)(u >> 16);
}

__device__ __forceinline__ void gload_lds16(const float* g, float* l) {
  __builtin_amdgcn_global_load_lds(
      (const __attribute__((address_space(1))) void*)g,
      (__attribute__((address_space(3))) void*)l, 16, 0, 0);
}

// ---------------------------------------------------------------------------
// Kernel 1: W [1024][128] fp32  ->  Wt [128][1024] bf16 (transposed)
// ---------------------------------------------------------------------------
__global__ __launch_bounds__(256) void convert_W(const float* __restrict__ W,
                                                 unsigned short* __restrict__ Wt) {
  int idx = blockIdx.x * 256 + threadIdx.x;      // over Wt, 131072 elems
  int n = idx >> 10;                              // 0..127
  int k = idx & 1023;                             // 0..1023
  Wt[idx] = f2bf(W[k * OUT_CH + n]);
}

// ---------------------------------------------------------------------------
// Kernel 2: adjacency build (edges + self-loops), atomic slot assignment
// ---------------------------------------------------------------------------
__global__ __launch_bounds__(256) void build_adj(const int* __restrict__ ei,
                                                 int* __restrict__ deg,
                                                 int* __restrict__ adj) {
  int i = blockIdx.x * blockDim.x + threadIdx.x;
  const int total = N_EDGES + N_NODES;
  if (i >= total) return;
  int src, dst;
  if (i < N_EDGES) { src = ei[i]; dst = ei[N_EDGES + i]; }
  else             { src = i - N_EDGES; dst = src; }     // self-loop
  int slot = atomicAdd(&deg[dst], 1);
  if (slot < MAX_DEG) adj[dst * MAX_DEG + slot] = src;
}

// ---------------------------------------------------------------------------
// Kernel 3: h = x @ W + b.  m97-style 2-phase double-buffered MFMA GEMM.
// BM=128 rows, all 128 cols, BK=64. 256 thr / 4 waves; wave w -> cols
// [32w, 32w+32). A staged fp32 via global_load_lds (linear dest, source
// pre-swizzled s=(row&7)<<4); ds_read side applies the same XOR -> 2-way
// bank conflicts (free). B direct from L2-resident Wt. Bias fused.
// ---------------------------------------------------------------------------
__global__ __launch_bounds__(256) void gemm_h(const float* __restrict__ x,
                                              const unsigned short* __restrict__ Wt,
                                              const float* __restrict__ bias,
                                              float* __restrict__ h) {
  __shared__ float smem[2 * BM * BK];             // 64 KB
  const int tid  = threadIdx.x;
  const int wave = tid >> 6;
  const int lane = tid & 63;
  const int l16  = lane & 15;
  const int g4   = lane >> 4;
  const int m0   = blockIdx.x * BM;
  const int trow = tid >> 4;                      // 0..15
  const int tcol = tid & 15;                      // 0..15

  f32x4 acc[8][2];
#pragma unroll
  for (int rf = 0; rf < 8; ++rf)
#pragma unroll
    for (int cf = 0; cf < 2; ++cf) acc[rf][cf] = (f32x4){0.f, 0.f, 0.f, 0.f};

  // --- stage K-step st into buffer buf (8 x global_load_lds per thread) ---
  auto stage = [&](int buf, int st) {
    const int k0 = st * BK;
#pragma unroll
    for (int r = 0; r < 8; ++r) {
      int row_t = r * 16 + trow;                            // tile row 0..127
      int row_g = m0 + row_t;
      if (row_g > N_NODES - 1) row_g = N_NODES - 1;         // tail clamp
      int ksw = (tcol ^ (row_t & 7)) << 2;                  // swizzled float idx
      const float* src = x + (size_t)row_g * IN_CH + k0 + ksw;
      float* dst = smem + buf * (BM * BK) + row_t * BK + tcol * 4;  // linear
      gload_lds16(src, dst);
    }
  };

  // --- compute K-step st from buffer buf ---
  auto compute = [&](int buf, int st) {
    const int k0 = st * BK;
    const char* sb = (const char*)(smem + buf * (BM * BK));
#pragma unroll
    for (int ks = 0; ks < 2; ++ks) {
      bf16x8 bfr[2];
#pragma unroll
      for (int cf = 0; cf < 2; ++cf) {
        int col = wave * 32 + cf * 16 + l16;
        ushort8 bu = *(const ushort8*)(Wt + (size_t)col * IN_CH + k0 + ks * 32 + g4 * 8);
        bfr[cf] = __builtin_bit_cast(bf16x8, bu);
      }
#pragma unroll
      for (int rf = 0; rf < 8; ++rf) {
        int row = rf * 16 + l16;
        int s   = (row & 7) << 4;
        int b0  = (row << 8) + ((ks * 32 + g4 * 8) << 2);
        f32x4 a0 = *(const f32x4*)(sb + ((b0) ^ s));
        f32x4 a1 = *(const f32x4*)(sb + ((b0 + 16) ^ s));
        ushort8 af;
        af[0] = f2bf(a0[0]); af[1] = f2bf(a0[1]); af[2] = f2bf(a0[2]); af[3] = f2bf(a0[3]);
        af[4] = f2bf(a1[0]); af[5] = f2bf(a1[1]); af[6] = f2bf(a1[2]); af[7] = f2bf(a1[3]);
        bf16x8 av = __builtin_bit_cast(bf16x8, af);
        acc[rf][0] = __builtin_amdgcn_mfma_f32_16x16x32_bf16(av, bfr[0], acc[rf][0], 0, 0, 0);
        acc[rf][1] = __builtin_amdgcn_mfma_f32_16x16x32_bf16(av, bfr[1], acc[rf][1], 0, 0, 0);
      }
    }
  };

  // prologue
  stage(0, 0);
  __syncthreads();                     // vmcnt(0) drain: buf0 ready
  int cur = 0;
  for (int st = 0; st < NSTEP - 1; ++st) {
    stage(cur ^ 1, st + 1);            // issue next tile BEFORE compute
    compute(cur, st);
    __syncthreads();                   // drains stage (hidden under compute)
    cur ^= 1;
  }
  compute(cur, NSTEP - 1);

  // epilogue: C/D layout col=lane&15, row=(lane>>4)*4+i (verified m89/m91)
  const int crow0 = m0 + g4 * 4;
#pragma unroll
  for (int cf = 0; cf < 2; ++cf) {
    const int col = wave * 32 + cf * 16 + l16;
    const float bv = bias[col];        // median(h+b) == median(h)+b
#pragma unroll
    for (int rf = 0; rf < 8; ++rf) {
#pragma unroll
      for (int i = 0; i < 4; ++i) {
        int r = crow0 + rf * 16 + i;
        if (r < N_NODES) h[(size_t)r * OUT_CH + col] = acc[rf][cf][i] + bv;
      }
    }
  }
}

// ---------------------------------------------------------------------------
// Kernel 4: per-node, per-channel lower median via register sorting network
// ---------------------------------------------------------------------------
template <int NS>
__device__ __forceinline__ void batcher_sort(float (&a)[NS]) {
#pragma unroll
  for (int p = 1; p < NS; p <<= 1) {
#pragma unroll
    for (int k = p; k >= 1; k >>= 1) {
#pragma unroll
      for (int j = k % p; j + k < NS; j += 2 * k) {
#pragma unroll
        for (int i = 0; i < k; ++i) {
          if (i + j + k < NS) {
            if ((i + j) / (2 * p) == (i + j + k) / (2 * p)) {
              float lo = fminf(a[i + j], a[i + j + k]);
              float hi = fmaxf(a[i + j], a[i + j + k]);
              a[i + j] = lo;
              a[i + j + k] = hi;
            }
          }
        }
      }
    }
  }
}

template <int NS>
__device__ __forceinline__ float med_n(const float* __restrict__ h,
                                       const int* nbrs, int d, int m, int ch) {
  float a[NS];
#pragma unroll
  for (int j = 0; j < NS; ++j) {
    if (j < d) a[j] = h[(size_t)nbrs[j] * OUT_CH + ch];
    else       a[j] = 1e30f;
  }
  batcher_sort<NS>(a);
  float med = a[0];
#pragma unroll
  for (int j = 1; j < NS; ++j) med = (j == m) ? a[j] : med;
  return med;
}

__global__ __launch_bounds__(128) void median_kernel(const float* __restrict__ h,
                                                     const int* __restrict__ adj,
                                                     const int* __restrict__ deg,
                                                     float* __restrict__ out) {
  __shared__ int nbrs[64];
  const int node = blockIdx.x;
  const int ch   = threadIdx.x;
  int d = deg[node];
  if (d > MAX_DEG) d = MAX_DEG;
  if (ch < 64) nbrs[ch] = (ch < d && ch < MAX_DEG) ? adj[node * MAX_DEG + ch] : 0;
  __syncthreads();
  const int m = (d - 1) >> 1;   // lower median index; d >= 1 (self-loop)

  float med;
  if (d <= 8)       med = med_n<8>(h, nbrs, d, m, ch);
  else if (d <= 16) med = med_n<16>(h, nbrs, d, m, ch);
  else if (d <= 32) med = med_n<32>(h, nbrs, d, m, ch);
  else              med = med_n<64>(h, nbrs, d, m, ch);

  out[(size_t)node * OUT_CH + ch] = med;
}

// ---------------------------------------------------------------------------
extern "C" void kernel_launch(void* const* d_in, const int* in_sizes, int n_in,
                              void* d_out, int out_size, void* d_ws, size_t ws_size,
                              hipStream_t stream) {
  const float* x  = (const float*)d_in[0];
  const int*   ei = (const int*)d_in[1];
  const float* W  = (const float*)d_in[2];
  const float* b  = (const float*)d_in[3];
  float* out = (float*)d_out;

  char* ws = (char*)d_ws;
  float*          h   = (float*)ws;                                  // 15,360,000 B
  unsigned short* Wt  = (unsigned short*)(ws + 15360000);             //    262,144 B
  int*            deg = (int*)(ws + 15360000 + 262144);               //    120,000 B
  int*            adj = (int*)(ws + 15360000 + 262144 + 120000);      //  5,760,000 B

  hipMemsetAsync(deg, 0, N_NODES * sizeof(int), stream);
  convert_W<<<dim3(131072 / 256), dim3(256), 0, stream>>>(W, Wt);
  build_adj<<<dim3((N_EDGES + N_NODES + 255) / 256), dim3(256), 0, stream>>>(ei, deg, adj);
  gemm_h<<<dim3((N_NODES + BM - 1) / BM), dim3(256), 0, stream>>>(x, Wt, b, h);
  median_kernel<<<dim3(N_NODES), dim3(128), 0, stream>>>(h, adj, deg, out);
}

// Round 4
// 273.936 us; speedup vs baseline: 1.1789x; 1.0762x over previous
//
#include <hip/hip_runtime.h>
#include <hip/hip_bf16.h>

#define N_NODES 30000
#define N_EDGES 480000
#define IN_CH   1024
#define OUT_CH  128
#define MAX_DEG 48

#define BM 64
#define BK 64
#define NSTEP (IN_CH / BK)   // 16

typedef float   f32x4  __attribute__((ext_vector_type(4)));
typedef __bf16  bf16x8 __attribute__((ext_vector_type(8)));
typedef unsigned short ushort8 __attribute__((ext_vector_type(8)));
typedef unsigned int   uint4v  __attribute__((ext_vector_type(4)));

__device__ __forceinline__ unsigned short f2bf(float f) {
  unsigned int u = __builtin_bit_cast(unsigned int, f);
  u += 0x7fffu + ((u >> 16) & 1u);          // RTNE
  return (unsigned short)(u >> 16);
}

__device__ __forceinline__ unsigned int cvt_pk(float lo, float hi) {
  unsigned int r;
  asm("v_cvt_pk_bf16_f32 %0, %1, %2" : "=v"(r) : "v"(lo), "v"(hi));
  return r;
}

__device__ __forceinline__ void gload_lds16(const void* g, void* l) {
  __builtin_amdgcn_global_load_lds(
      (const __attribute__((address_space(1))) void*)g,
      (__attribute__((address_space(3))) void*)l, 16, 0, 0);
}

// ---------------------------------------------------------------------------
// Kernel 1: W [1024][128] fp32  ->  Wt [128][1024] bf16 (transposed)
// ---------------------------------------------------------------------------
__global__ __launch_bounds__(256) void convert_W(const float* __restrict__ W,
                                                 unsigned short* __restrict__ Wt) {
  int idx = blockIdx.x * 256 + threadIdx.x;      // over Wt, 131072 elems
  int n = idx >> 10;                              // 0..127
  int k = idx & 1023;                             // 0..1023
  Wt[idx] = f2bf(W[k * OUT_CH + n]);
}

// ---------------------------------------------------------------------------
// Kernel 2: adjacency build (edges + self-loops), atomic slot assignment
// ---------------------------------------------------------------------------
__global__ __launch_bounds__(256) void build_adj(const int* __restrict__ ei,
                                                 int* __restrict__ deg,
                                                 int* __restrict__ adj) {
  int i = blockIdx.x * blockDim.x + threadIdx.x;
  const int total = N_EDGES + N_NODES;
  if (i >= total) return;
  int src, dst;
  if (i < N_EDGES) { src = ei[i]; dst = ei[N_EDGES + i]; }
  else             { src = i - N_EDGES; dst = src; }     // self-loop
  int slot = atomicAdd(&deg[dst], 1);
  if (slot < MAX_DEG) adj[dst * MAX_DEG + slot] = src;
}

// ---------------------------------------------------------------------------
// Kernel 3: h = x @ W + b.  BM=64 (469 blocks, 2 blocks/CU), BK=64.
// BOTH A (fp32, 16KB/step) and B (bf16, 16KB/step) staged async via
// global_load_lds into a 2-deep double buffer (64 KB LDS). Linear LDS dest;
// global source pre-swizzled; ds_read applies same XOR (rule #21).
// A swizzle: slot(4b) ^= row&15 (4-way). B swizzle: slot(3b) ^= col&7.
// Nothing global sits on the MFMA dependent path. Bias fused.
// ---------------------------------------------------------------------------
__global__ __launch_bounds__(256) void gemm_h(const float* __restrict__ x,
                                              const unsigned short* __restrict__ Wt,
                                              const float* __restrict__ bias,
                                              float* __restrict__ h) {
  // [2 bufs][ A: 64 rows * 256B | B: 128 cols * 128B ]
  __shared__ char smem[2 * 32768];
  const int tid  = threadIdx.x;
  const int wv   = tid >> 6;
  const int lane = tid & 63;
  const int l16  = lane & 15;
  const int g4   = lane >> 4;
  const int m0   = blockIdx.x * BM;

  f32x4 acc[4][2];
#pragma unroll
  for (int rf = 0; rf < 4; ++rf)
#pragma unroll
    for (int cf = 0; cf < 2; ++cf) acc[rf][cf] = (f32x4){0.f, 0.f, 0.f, 0.f};

  // --- stage K-step st into buffer buf: 4 A-loads + 4 B-loads per thread ---
  auto stage = [&](int buf, int st) {
    const int k0 = st * BK;
    char* sA = smem + buf * 32768;
    char* sB = sA + 16384;
#pragma unroll
    for (int j = 0; j < 4; ++j) {
      const int blk = wv * 4 + j;
      // A: linear LDS byte = blk*1024 + lane*16  ->  [rowA][(lane&15)*16B]
      const int rowA = blk * 4 + (lane >> 4);
      int rg = m0 + rowA;
      if (rg > N_NODES - 1) rg = N_NODES - 1;               // tail clamp
      const float* srcA = x + (size_t)rg * IN_CH + k0
                        + (((lane & 15) ^ (rowA & 15)) << 2);
      gload_lds16(srcA, sA + blk * 1024 + lane * 16);
      // B: linear LDS byte = blk*1024 + lane*16  ->  [c][(lane&7)*16B]
      const int c = blk * 8 + (lane >> 3);
      const unsigned short* srcB = Wt + (size_t)c * IN_CH + k0
                                 + (((lane & 7) ^ (c & 7)) << 3);
      gload_lds16(srcB, sB + blk * 1024 + lane * 16);
    }
  };

  // --- compute from buffer buf (LDS + MFMA only) ---
  auto compute = [&](int buf) {
    const char* sA = smem + buf * 32768;
    const char* sB = sA + 16384;
#pragma unroll
    for (int ks = 0; ks < 2; ++ks) {
      bf16x8 bfr[2];
#pragma unroll
      for (int cf = 0; cf < 2; ++cf) {
        const int c = wv * 32 + cf * 16 + l16;
        const int slot = (ks * 4 + g4) ^ (c & 7);
        bfr[cf] = *(const bf16x8*)(sB + c * 128 + slot * 16);
      }
#pragma unroll
      for (int rf = 0; rf < 4; ++rf) {
        const int row = rf * 16 + l16;
        const int q0 = ((ks * 8 + g4 * 2) ^ (row & 15)) << 4;
        const int q1 = ((ks * 8 + g4 * 2 + 1) ^ (row & 15)) << 4;
        f32x4 a0 = *(const f32x4*)(sA + row * 256 + q0);
        f32x4 a1 = *(const f32x4*)(sA + row * 256 + q1);
        uint4v aw;
        aw[0] = cvt_pk(a0[0], a0[1]);
        aw[1] = cvt_pk(a0[2], a0[3]);
        aw[2] = cvt_pk(a1[0], a1[1]);
        aw[3] = cvt_pk(a1[2], a1[3]);
        bf16x8 av = __builtin_bit_cast(bf16x8, aw);
        acc[rf][0] = __builtin_amdgcn_mfma_f32_16x16x32_bf16(av, bfr[0], acc[rf][0], 0, 0, 0);
        acc[rf][1] = __builtin_amdgcn_mfma_f32_16x16x32_bf16(av, bfr[1], acc[rf][1], 0, 0, 0);
      }
    }
  };

  // prologue
  stage(0, 0);
  __syncthreads();                     // vmcnt(0) drain: buf0 ready
  int cur = 0;
  for (int st = 0; st < NSTEP - 1; ++st) {
    stage(cur ^ 1, st + 1);            // issue next tile BEFORE compute
    compute(cur);
    __syncthreads();                   // drain hidden under compute + other block
    cur ^= 1;
  }
  compute(cur);

  // epilogue: C/D layout col=lane&15, row=(lane>>4)*4+i (verified m89/m91)
  const int crow0 = m0 + g4 * 4;
#pragma unroll
  for (int cf = 0; cf < 2; ++cf) {
    const int col = wv * 32 + cf * 16 + l16;
    const float bv = bias[col];        // median(h+b) == median(h)+b
#pragma unroll
    for (int rf = 0; rf < 4; ++rf) {
#pragma unroll
      for (int i = 0; i < 4; ++i) {
        int r = crow0 + rf * 16 + i;
        if (r < N_NODES) h[(size_t)r * OUT_CH + col] = acc[rf][cf][i] + bv;
      }
    }
  }
}

// ---------------------------------------------------------------------------
// Kernel 4: per-node, per-channel lower median via register sorting network
// ---------------------------------------------------------------------------
template <int NS>
__device__ __forceinline__ void batcher_sort(float (&a)[NS]) {
#pragma unroll
  for (int p = 1; p < NS; p <<= 1) {
#pragma unroll
    for (int k = p; k >= 1; k >>= 1) {
#pragma unroll
      for (int j = k % p; j + k < NS; j += 2 * k) {
#pragma unroll
        for (int i = 0; i < k; ++i) {
          if (i + j + k < NS) {
            if ((i + j) / (2 * p) == (i + j + k) / (2 * p)) {
              float lo = fminf(a[i + j], a[i + j + k]);
              float hi = fmaxf(a[i + j], a[i + j + k]);
              a[i + j] = lo;
              a[i + j + k] = hi;
            }
          }
        }
      }
    }
  }
}

template <int NS>
__device__ __forceinline__ float med_n(const float* __restrict__ h,
                                       const int* nbrs, int d, int m, int ch) {
  float a[NS];
#pragma unroll
  for (int j = 0; j < NS; ++j) {
    if (j < d) a[j] = h[(size_t)nbrs[j] * OUT_CH + ch];
    else       a[j] = 1e30f;
  }
  batcher_sort<NS>(a);
  float med = a[0];
#pragma unroll
  for (int j = 1; j < NS; ++j) med = (j == m) ? a[j] : med;
  return med;
}

__global__ __launch_bounds__(128) void median_kernel(const float* __restrict__ h,
                                                     const int* __restrict__ adj,
                                                     const int* __restrict__ deg,
                                                     float* __restrict__ out) {
  __shared__ int nbrs[64];
  const int node = blockIdx.x;
  const int ch   = threadIdx.x;
  int d = deg[node];
  if (d > MAX_DEG) d = MAX_DEG;
  if (ch < 64) nbrs[ch] = (ch < d && ch < MAX_DEG) ? adj[node * MAX_DEG + ch] : 0;
  __syncthreads();
  const int m = (d - 1) >> 1;   // lower median index; d >= 1 (self-loop)

  float med;
  if (d <= 8)       med = med_n<8>(h, nbrs, d, m, ch);
  else if (d <= 16) med = med_n<16>(h, nbrs, d, m, ch);
  else if (d <= 32) med = med_n<32>(h, nbrs, d, m, ch);
  else              med = med_n<64>(h, nbrs, d, m, ch);

  out[(size_t)node * OUT_CH + ch] = med;
}

// ---------------------------------------------------------------------------
extern "C" void kernel_launch(void* const* d_in, const int* in_sizes, int n_in,
                              void* d_out, int out_size, void* d_ws, size_t ws_size,
                              hipStream_t stream) {
  const float* x  = (const float*)d_in[0];
  const int*   ei = (const int*)d_in[1];
  const float* W  = (const float*)d_in[2];
  const float* b  = (const float*)d_in[3];
  float* out = (float*)d_out;

  char* ws = (char*)d_ws;
  float*          h   = (float*)ws;                                  // 15,360,000 B
  unsigned short* Wt  = (unsigned short*)(ws + 15360000);             //    262,144 B
  int*            deg = (int*)(ws + 15360000 + 262144);               //    120,000 B
  int*            adj = (int*)(ws + 15360000 + 262144 + 120000);      //  5,760,000 B

  hipMemsetAsync(deg, 0, N_NODES * sizeof(int), stream);
  convert_W<<<dim3(131072 / 256), dim3(256), 0, stream>>>(W, Wt);
  build_adj<<<dim3((N_EDGES + N_NODES + 255) / 256), dim3(256), 0, stream>>>(ei, deg, adj);
  gemm_h<<<dim3((N_NODES + BM - 1) / BM), dim3(256), 0, stream>>>(x, Wt, b, h);
  median_kernel<<<dim3(N_NODES), dim3(128), 0, stream>>>(h, adj, deg, out);
}

// Round 7
// 251.423 us; speedup vs baseline: 1.2845x; 1.0895x over previous
//
#include <hip/hip_runtime.h>
#include <hip/hip_bf16.h>

#define N_NODES 30000
#define N_EDGES 480000
#define IN_CH   1024
#define OUT_CH  128
#define MAX_DEG 48

#define BM 32
#define BK 64
#define NSTEP (IN_CH / BK)   // 16

typedef float   f32x4  __attribute__((ext_vector_type(4)));
typedef float   f32x2  __attribute__((ext_vector_type(2)));
typedef __bf16  bf16x8 __attribute__((ext_vector_type(8)));
typedef unsigned short ushort8 __attribute__((ext_vector_type(8)));
typedef unsigned int   uint4v  __attribute__((ext_vector_type(4)));

__device__ __forceinline__ unsigned short f2bf(float f) {
  unsigned int u = __builtin_bit_cast(unsigned int, f);
  u += 0x7fffu + ((u >> 16) & 1u);          // RTNE
  return (unsigned short)(u >> 16);
}

__device__ __forceinline__ unsigned int cvt_pk(float lo, float hi) {
  unsigned int r;
  asm("v_cvt_pk_bf16_f32 %0, %1, %2" : "=v"(r) : "v"(lo), "v"(hi));
  return r;
}

__device__ __forceinline__ unsigned pk_min(unsigned a, unsigned b) {
  unsigned r; asm("v_pk_min_f16 %0, %1, %2" : "=v"(r) : "v"(a), "v"(b)); return r;
}
__device__ __forceinline__ unsigned pk_max(unsigned a, unsigned b) {
  unsigned r; asm("v_pk_max_f16 %0, %1, %2" : "=v"(r) : "v"(a), "v"(b)); return r;
}
__device__ __forceinline__ float f16_to_f32(unsigned u16) {  // low 16 bits
  float f; asm("v_cvt_f32_f16 %0, %1" : "=v"(f) : "v"(u16)); return f;
}
__device__ __forceinline__ unsigned short f32_to_f16(float f) {
  unsigned r; asm("v_cvt_f16_f32 %0, %1" : "=v"(r) : "v"(f));
  return (unsigned short)(r & 0xffffu);
}

__device__ __forceinline__ void gload_lds16(const void* g, void* l) {
  __builtin_amdgcn_global_load_lds(
      (const __attribute__((address_space(1))) void*)g,
      (__attribute__((address_space(3))) void*)l, 16, 0, 0);
}

// ---------------------------------------------------------------------------
// Kernel 1: W [1024][128] f32 -> Wtt [k/8][128 cols][8] bf16 (tiled transpose)
// LDS transpose tile: coalesced global reads AND writes.
// ---------------------------------------------------------------------------
__global__ __launch_bounds__(256) void convert_W(const float* __restrict__ W,
                                                 unsigned short* __restrict__ Wtt) {
  __shared__ float tile[64][132];                 // +4 pad: banks rotate
  const int tid = threadIdx.x;
  const int k0  = blockIdx.x * 64;
#pragma unroll
  for (int it = 0; it < 32; ++it) {
    int id = it * 256 + tid;                      // 8192 elems
    int kk = id >> 7, n = id & 127;
    tile[kk][n] = W[(size_t)(k0 + kk) * OUT_CH + n];
  }
  __syncthreads();
#pragma unroll
  for (int it = 0; it < 4; ++it) {
    int id8 = it * 256 + tid;                     // 1024 groups of 8
    int kc = id8 >> 7, n = id8 & 127;
    ushort8 v;
#pragma unroll
    for (int kd = 0; kd < 8; ++kd) v[kd] = f2bf(tile[kc * 8 + kd][n]);
    *(ushort8*)(Wtt + (size_t)k0 * 128 + id8 * 8) = v;
  }
}

// ---------------------------------------------------------------------------
// Kernel 2: adjacency build (edges + self-loops), atomic slot assignment
// ---------------------------------------------------------------------------
__global__ __launch_bounds__(256) void build_adj(const int* __restrict__ ei,
                                                 int* __restrict__ deg,
                                                 int* __restrict__ adj) {
  int i = blockIdx.x * blockDim.x + threadIdx.x;
  const int total = N_EDGES + N_NODES;
  if (i >= total) return;
  int src, dst;
  if (i < N_EDGES) { src = ei[i]; dst = ei[N_EDGES + i]; }
  else             { src = i - N_EDGES; dst = src; }     // self-loop
  int slot = atomicAdd(&deg[dst], 1);
  if (slot < MAX_DEG) adj[dst * MAX_DEG + slot] = src;
}

// ---------------------------------------------------------------------------
// Kernel 3: h16 = f16(x @ W + b).  BM=32 (938 blocks ~15 waves/CU), BK=64.
// A staged via global_load_lds into 2-deep dbuf (16 KB LDS), source
// pre-swizzled slot^=(row&15), same XOR on ds_read (rule #21, involution).
// B prefetched 2 steps ahead into registers from coalesced Wtt tiles.
// Main loop: counted s_waitcnt vmcnt(6) + raw s_barrier (T4) — 6 loads
// stay in flight across barriers; vmcnt(0) only at the final step.
// ---------------------------------------------------------------------------
__global__ __launch_bounds__(256) void gemm_h(const float* __restrict__ x,
                                              const unsigned short* __restrict__ Wtt,
                                              const float* __restrict__ bias,
                                              unsigned short* __restrict__ h16) {
  __shared__ float sA[2][BM * BK];                // 2 x 8 KB
  const int tid  = threadIdx.x;
  const int wv   = tid >> 6;
  const int lane = tid & 63;
  const int l16  = lane & 15;
  const int g4   = lane >> 4;
  const int m0   = blockIdx.x * BM;

  f32x4 acc[2][2];
#pragma unroll
  for (int rf = 0; rf < 2; ++rf)
#pragma unroll
    for (int cf = 0; cf < 2; ++cf) acc[rf][cf] = (f32x4){0.f, 0.f, 0.f, 0.f};

  auto stageA = [&](int p, int st) {              // 2 x gload_lds per thread
#pragma unroll
    for (int j = 0; j < 2; ++j) {
      const int blk  = wv * 2 + j;                // 1KB block 0..7
      const int rowA = blk * 4 + g4;              // 0..31
      int rg = m0 + rowA;
      if (rg > N_NODES - 1) rg = N_NODES - 1;     // tail clamp
      const float* src = x + (size_t)rg * IN_CH + st * BK
                       + ((l16 ^ (rowA & 15)) << 2);
      gload_lds16(src, (char*)&sA[p][0] + blk * 1024 + lane * 16);
    }
  };
  auto loadB = [&](bf16x8 (&B)[2][2], int st) {   // 4 x b128 per thread
#pragma unroll
    for (int cf = 0; cf < 2; ++cf)
#pragma unroll
      for (int ks = 0; ks < 2; ++ks) {
        const int col = wv * 32 + cf * 16 + l16;
        const int kc  = st * 8 + ks * 4 + g4;     // k/8
        B[cf][ks] = *(const bf16x8*)(Wtt + ((size_t)kc * 128 + col) * 8);
      }
  };
  auto compute = [&](int p, bf16x8 (&B)[2][2]) {
    const char* base = (const char*)&sA[p][0];
#pragma unroll
    for (int ks = 0; ks < 2; ++ks)
#pragma unroll
      for (int rf = 0; rf < 2; ++rf) {
        const int row = rf * 16 + l16;
        const int s0  = ks * 8 + g4 * 2;
        f32x4 a0 = *(const f32x4*)(base + row * 256 + (((s0    ) ^ (row & 15)) << 4));
        f32x4 a1 = *(const f32x4*)(base + row * 256 + (((s0 + 1) ^ (row & 15)) << 4));
        uint4v aw;
        aw[0] = cvt_pk(a0[0], a0[1]); aw[1] = cvt_pk(a0[2], a0[3]);
        aw[2] = cvt_pk(a1[0], a1[1]); aw[3] = cvt_pk(a1[2], a1[3]);
        bf16x8 av = __builtin_bit_cast(bf16x8, aw);
        acc[rf][0] = __builtin_amdgcn_mfma_f32_16x16x32_bf16(av, B[0][ks], acc[rf][0], 0, 0, 0);
        acc[rf][1] = __builtin_amdgcn_mfma_f32_16x16x32_bf16(av, B[1][ks], acc[rf][1], 0, 0, 0);
      }
  };

#define WAIT6_BAR() asm volatile("s_waitcnt vmcnt(6)\ns_barrier" ::: "memory")
#define WAIT0_BAR() asm volatile("s_waitcnt vmcnt(0)\ns_barrier" ::: "memory")
#define BAR()       asm volatile("s_barrier" ::: "memory")

  bf16x8 B0[2][2], B1[2][2];
  // prologue: steps 0 and 1 in flight (12 vmem)
  stageA(0, 0); loadB(B0, 0);
  stageA(1, 1); loadB(B1, 1);
  // steps 0..13: 7 double-iterations, stage/prefetch 2 ahead
#pragma unroll
  for (int s2 = 0; s2 < 7; ++s2) {
    const int se = s2 * 2;
    WAIT6_BAR();                       // step se ready; se+1's 6 in flight
    compute(0, B0);
    BAR();                             // all waves done reading buf0
    stageA(0, se + 2); loadB(B0, se + 2);
    WAIT6_BAR();                       // step se+1 ready; se+2's 6 in flight
    compute(1, B1);
    BAR();                             // all waves done reading buf1
    stageA(1, se + 3); loadB(B1, se + 3);
  }
  WAIT6_BAR();  compute(0, B0);        // step 14 (15's 6 in flight)
  WAIT0_BAR();  compute(1, B1);        // step 15 (full drain, last)

  // epilogue: C/D layout col=lane&15, row=(lane>>4)*4+i (verified m89/m91)
  const int r0 = m0 + g4 * 4;
#pragma unroll
  for (int cf = 0; cf < 2; ++cf) {
    const int col = wv * 32 + cf * 16 + l16;
    const float bv = bias[col];        // median(h+b) == median(h)+b
#pragma unroll
    for (int rf = 0; rf < 2; ++rf)
#pragma unroll
      for (int i = 0; i < 4; ++i) {
        int r = r0 + rf * 16 + i;
        if (r < N_NODES)
          h16[(size_t)r * OUT_CH + col] = f32_to_f16(acc[rf][cf][i] + bv);
      }
  }
#undef WAIT6_BAR
#undef WAIT0_BAR
#undef BAR
}

// ---------------------------------------------------------------------------
// Kernel 4: lower median per (node, channel-pair) via packed-f16 sort network.
// 1 wave per node; lane owns channels {2*lane, 2*lane+1} as one u32;
// v_pk_min/max_f16 sorts both channels at once.
// ---------------------------------------------------------------------------
template <int NS>
__device__ __forceinline__ void sortnet(unsigned (&a)[NS]) {
#pragma unroll
  for (int p = 1; p < NS; p <<= 1) {
#pragma unroll
    for (int k = p; k >= 1; k >>= 1) {
#pragma unroll
      for (int j = k % p; j + k < NS; j += 2 * k) {
#pragma unroll
        for (int i = 0; i < k; ++i) {
          if (i + j + k < NS) {
            if ((i + j) / (2 * p) == (i + j + k) / (2 * p)) {
              unsigned lo = pk_min(a[i + j], a[i + j + k]);
              unsigned hi = pk_max(a[i + j], a[i + j + k]);
              a[i + j] = lo;
              a[i + j + k] = hi;
            }
          }
        }
      }
    }
  }
}

template <int NS>
__device__ __forceinline__ unsigned med_n(const unsigned short* __restrict__ h16,
                                          const int* nb, int d, int m, int lane) {
  unsigned a[NS];
#pragma unroll
  for (int j = 0; j < NS; ++j) {
    // nb[j] is a valid node id even for j>=d (padded with self) -> safe load
    unsigned v = *(const unsigned*)(h16 + (size_t)nb[j] * OUT_CH + lane * 2);
    a[j] = (j < d) ? v : 0x7C007C00u;             // +inf f16 pair
  }
  sortnet<NS>(a);
  unsigned med = a[0];
#pragma unroll
  for (int j = 1; j < NS; ++j) med = (j == m) ? a[j] : med;
  return med;
}

__global__ __launch_bounds__(256) void median_kernel(const unsigned short* __restrict__ h16,
                                                     const int* __restrict__ adj,
                                                     const int* __restrict__ deg,
                                                     float* __restrict__ out) {
  __shared__ int nb[4][MAX_DEG];
  const int wv   = threadIdx.x >> 6;
  const int lane = threadIdx.x & 63;
  const int node = blockIdx.x * 4 + wv;

  int d = deg[node];                   // wave-uniform
  if (d > MAX_DEG) d = MAX_DEG;
  if (lane < MAX_DEG)
    nb[wv][lane] = (lane < d) ? adj[node * MAX_DEG + lane] : node;  // pad = self
  // nb[wv] is wave-private; in-wave ds ordering handled by compiler (lgkmcnt)
  const int m = (d - 1) >> 1;          // lower median; d >= 1 (self-loop)

  unsigned med;
  if (d <= 16)      med = med_n<16>(h16, nb[wv], d, m, lane);
  else if (d <= 24) med = med_n<24>(h16, nb[wv], d, m, lane);
  else if (d <= 32) med = med_n<32>(h16, nb[wv], d, m, lane);
  else              med = med_n<48>(h16, nb[wv], d, m, lane);

  f32x2 o;
  o[0] = f16_to_f32(med & 0xffffu);
  o[1] = f16_to_f32(med >> 16);
  *(f32x2*)(out + (size_t)node * OUT_CH + lane * 2) = o;
}

// ---------------------------------------------------------------------------
extern "C" void kernel_launch(void* const* d_in, const int* in_sizes, int n_in,
                              void* d_out, int out_size, void* d_ws, size_t ws_size,
                              hipStream_t stream) {
  const float* x  = (const float*)d_in[0];
  const int*   ei = (const int*)d_in[1];
  const float* W  = (const float*)d_in[2];
  const float* b  = (const float*)d_in[3];
  float* out = (float*)d_out;

  char* ws = (char*)d_ws;
  unsigned short* h16 = (unsigned short*)ws;                         //  7,680,000 B
  unsigned short* Wtt = (unsigned short*)(ws + 7680000);             //    262,144 B
  int*            deg = (int*)(ws + 7680000 + 262144);               //    120,000 B
  int*            adj = (int*)(ws + 7680000 + 262144 + 120000);      //  5,760,000 B

  (void)hipMemsetAsync(deg, 0, N_NODES * sizeof(int), stream);
  convert_W<<<dim3(IN_CH / 64), dim3(256), 0, stream>>>(W, Wtt);
  build_adj<<<dim3((N_EDGES + N_NODES + 255) / 256), dim3(256), 0, stream>>>(ei, deg, adj);
  gemm_h<<<dim3((N_NODES + BM - 1) / BM), dim3(256), 0, stream>>>(x, Wtt, b, h16);
  median_kernel<<<dim3(N_NODES / 4), dim3(256), 0, stream>>>(h16, adj, deg, out);
}